// Round 10
// baseline (88.660 us; speedup 1.0000x reference)
//
#include <hip/hip_runtime.h>

#define SQd 4096
#define SKVd 4096
#define DDIM 64
#define BK 32                          // keys per tile
#define NG 8                           // key groups (waves) per block
#define NTILES (SKVd / BK)             // 128 tiles per batch
#define TPG (NTILES / NG)              // 16 tiles per wave
#define TILE_BYTES 2048                // per operand: 2 superfrags x 1024 B
#define KWS_BYTES (4 * NTILES * TILE_BYTES)   // 1 MB per operand
#define BROWS 32                       // q-rows per block (2 qg per wave)

typedef float floatx4 __attribute__((ext_vector_type(4)));

__device__ inline long long mk64(int lo, int hi) {
    int2 t; t.x = lo; t.y = hi;
    return __builtin_bit_cast(long long, t);
}
// Word-select must be an immediate constant -> template parameter.
template <bool HI>
__device__ inline int pk2(float a, float b, int old) {
    return __builtin_amdgcn_cvt_pk_fp8_f32(a, b, old, HI);
}

// LDS: cross-group combine only (8 key-groups -> 4 slots, 2 rounds).
struct CombS {
    float Ored[BROWS][4][68];
    float Lred[BROWS][NG];
};

// ---------------- Pre-pass: pack K and V into fp8 MFMA superfrags ----------
// (unchanged from R8/R9 — verified correct)
__global__ __launch_bounds__(256)
void prepack_kernel(const float* __restrict__ k, const float* __restrict__ v,
                    char* __restrict__ ws)
{
    __shared__ __align__(16) float Kt[BK][68];
    __shared__ __align__(16) float Vt[BK][68];

    const int blk  = blockIdx.x;          // b*NTILES + tile
    const int b    = blk >> 7;
    const int tile = blk & (NTILES - 1);
    const int tid  = threadIdx.x;

    const size_t base = ((size_t)b * SKVd + tile * BK) * DDIM;
    {
        const int row = tid >> 3, col = (tid & 7) * 8;
        const float4 k0 = *(const float4*)(k + base + (size_t)row * DDIM + col);
        const float4 k1 = *(const float4*)(k + base + (size_t)row * DDIM + col + 4);
        *(float4*)&Kt[row][col] = k0; *(float4*)&Kt[row][col + 4] = k1;
        const float4 v0 = *(const float4*)(v + base + (size_t)row * DDIM + col);
        const float4 v1 = *(const float4*)(v + base + (size_t)row * DDIM + col + 4);
        *(float4*)&Vt[row][col] = v0; *(float4*)&Vt[row][col + 4] = v1;
    }
    __syncthreads();

    const int lane = tid & 63;
    const int l16  = lane & 15;
    const int quad = lane >> 4;
    const int f    = tid >> 6;            // 0,1: K kh; 2,3: V pair

    int w[4];
    size_t off;
    if (f < 2) {
        const float* s0 = &Kt[f * 16 + l16][quad * 8];        // dh0
        const float* s1 = &Kt[f * 16 + l16][32 + quad * 8];   // dh1
        w[0] = pk2<false>(s0[0], s0[1], 0); w[0] = pk2<true>(s0[2], s0[3], w[0]);
        w[1] = pk2<false>(s0[4], s0[5], 0); w[1] = pk2<true>(s0[6], s0[7], w[1]);
        w[2] = pk2<false>(s1[0], s1[1], 0); w[2] = pk2<true>(s1[2], s1[3], w[2]);
        w[3] = pk2<false>(s1[4], s1[5], 0); w[3] = pk2<true>(s1[6], s1[7], w[3]);
        off = ((size_t)(b * NTILES + tile) * 2 + f) * 1024 + lane * 16;
    } else {
        const int p = f - 2;
        float vv[16];
        #pragma unroll
        for (int j2 = 0; j2 < 16; ++j2) {
            const int nb = 2 * p + (j2 >> 3);
            const int j  = j2 & 7;
            vv[j2] = Vt[16 * (j >> 2) + quad * 4 + (j & 3)][nb * 16 + l16];
        }
        #pragma unroll
        for (int i = 0; i < 4; ++i) {
            w[i] = pk2<false>(vv[4 * i], vv[4 * i + 1], 0);
            w[i] = pk2<true>(vv[4 * i + 2], vv[4 * i + 3], w[i]);
        }
        off = (size_t)KWS_BYTES + ((size_t)(b * NTILES + tile) * 2 + p) * 1024 + lane * 16;
    }
    int4 o4; o4.x = w[0]; o4.y = w[1]; o4.z = w[2]; o4.w = w[3];
    *(int4*)(ws + off) = o4;
}

// ---------------- Main kernel ---------------------------------------------
// Wave = 32 q-rows x 512 keys. Macro-step = 2 tiles: K prefetch at step start,
// QK+exp+pack for BOTH tiles as one independent block, V prefetch, then both
// PVs. Halves dependency joins vs R9; V waits never block QK.
__global__ __launch_bounds__(512, 4)
void fattn_kernel(const float* __restrict__ q, const int* __restrict__ isf_p,
                  const char* __restrict__ kws, const char* __restrict__ vws,
                  float* __restrict__ out)
{
    __shared__ __align__(16) CombS C;

    const int tid  = threadIdx.x;
    const int g    = tid >> 6;    // key group 0..7 (512 keys)
    const int lane = tid & 63;
    const int l16  = lane & 15;
    const int quad = lane >> 4;

    const int bidx  = blockIdx.x;       // 0..511
    const int b     = bidx >> 7;        // batch
    const int qbase = (bidx & 127) * BROWS;

    // exp(s) = 2^(s*log2e); constant -4 folded into the MFMA C-init keeps
    // p' = e^(s-4) within e4m3 range.
    const float scale = 1.44269504088896340736f / (float)(*isf_p);
    const float SINIT = -4.0f * 1.44269504088896340736f;

    long long qf[2][2];
    #pragma unroll
    for (int qg = 0; qg < 2; ++qg) {
        const int qrow = qbase + qg * 16 + l16;
        const float* qp = q + ((size_t)b * SQd + qrow) * DDIM + quad * 8;
        #pragma unroll
        for (int dh = 0; dh < 2; ++dh) {
            const float4 a0 = *(const float4*)(qp + dh * 32);
            const float4 a1 = *(const float4*)(qp + dh * 32 + 4);
            int lo = pk2<false>(a0.x * scale, a0.y * scale, 0);
            lo     = pk2<true>(a0.z * scale, a0.w * scale, lo);
            int hi = pk2<false>(a1.x * scale, a1.y * scale, 0);
            hi     = pk2<true>(a1.z * scale, a1.w * scale, hi);
            qf[qg][dh] = mk64(lo, hi);
        }
    }

    const char* kg = kws + (size_t)(b * NTILES + g * TPG) * TILE_BYTES + lane * 16;
    const char* vg = vws + (size_t)(b * NTILES + g * TPG) * TILE_BYTES + lane * 16;

    floatx4 o[2][4];
    float l_acc[2];
    #pragma unroll
    for (int qg = 0; qg < 2; ++qg) {
        l_acc[qg] = 0.0f;
        #pragma unroll
        for (int nb = 0; nb < 4; ++nb)
            #pragma unroll
            for (int r = 0; r < 4; ++r) o[qg][nb][r] = 0.0f;
    }
    const floatx4 sinit = {SINIT, SINIT, SINIT, SINIT};

    // Load one PAIR of tiles (4 int4 = 2 tiles x 2 superfrags).
    auto loadPair = [&](int4* d, const char* base_p, int pair) {
        const size_t off = (size_t)pair * (2 * TILE_BYTES);
        d[0] = *(const int4*)(base_p + off);
        d[1] = *(const int4*)(base_p + off + 1024);
        d[2] = *(const int4*)(base_p + off + 2048);
        d[3] = *(const int4*)(base_p + off + 3072);
    };

    // One macro-step: compute tile pair in (ck,cv); prefetch pair pn into (nk,nv).
    auto macro = [&](const int4* ck, const int4* cv, int4* nk, int4* nv, int pn) {
        loadPair(nk, kg, pn);            // K prefetch first — never blocks QK below
        long long pf[2][2];              // [tile][qg]
        #pragma unroll
        for (int i = 0; i < 2; ++i) {    // QK + exp + pack phase, both tiles
            const long long k00 = mk64(ck[2*i].x,   ck[2*i].y);
            const long long k01 = mk64(ck[2*i].z,   ck[2*i].w);
            const long long k10 = mk64(ck[2*i+1].x, ck[2*i+1].y);
            const long long k11 = mk64(ck[2*i+1].z, ck[2*i+1].w);
            #pragma unroll
            for (int qg = 0; qg < 2; ++qg) {
                floatx4 s0 = sinit, s1 = sinit;
                s0 = __builtin_amdgcn_mfma_f32_16x16x32_fp8_fp8(k00, qf[qg][0], s0, 0, 0, 0);
                s0 = __builtin_amdgcn_mfma_f32_16x16x32_fp8_fp8(k01, qf[qg][1], s0, 0, 0, 0);
                s1 = __builtin_amdgcn_mfma_f32_16x16x32_fp8_fp8(k10, qf[qg][0], s1, 0, 0, 0);
                s1 = __builtin_amdgcn_mfma_f32_16x16x32_fp8_fp8(k11, qf[qg][1], s1, 0, 0, 0);
                const float p00 = __builtin_amdgcn_exp2f(s0[0]);
                const float p01 = __builtin_amdgcn_exp2f(s0[1]);
                const float p02 = __builtin_amdgcn_exp2f(s0[2]);
                const float p03 = __builtin_amdgcn_exp2f(s0[3]);
                const float p10 = __builtin_amdgcn_exp2f(s1[0]);
                const float p11 = __builtin_amdgcn_exp2f(s1[1]);
                const float p12 = __builtin_amdgcn_exp2f(s1[2]);
                const float p13 = __builtin_amdgcn_exp2f(s1[3]);
                l_acc[qg] += (p00 + p01) + (p02 + p03) + (p10 + p11) + (p12 + p13);
                int lo = pk2<false>(p00, p01, 0); lo = pk2<true>(p02, p03, lo);
                int hi = pk2<false>(p10, p11, 0); hi = pk2<true>(p12, p13, hi);
                pf[i][qg] = mk64(lo, hi);
            }
        }
        loadPair(nv, vg, pn);            // V prefetch after QK — its wait is late
        #pragma unroll
        for (int i = 0; i < 2; ++i) {    // PV phase, both tiles
            const long long v0 = mk64(cv[2*i].x,   cv[2*i].y);
            const long long v1 = mk64(cv[2*i].z,   cv[2*i].w);
            const long long v2 = mk64(cv[2*i+1].x, cv[2*i+1].y);
            const long long v3 = mk64(cv[2*i+1].z, cv[2*i+1].w);
            #pragma unroll
            for (int qg = 0; qg < 2; ++qg) {
                o[qg][0] = __builtin_amdgcn_mfma_f32_16x16x32_fp8_fp8(pf[i][qg], v0, o[qg][0], 0, 0, 0);
                o[qg][1] = __builtin_amdgcn_mfma_f32_16x16x32_fp8_fp8(pf[i][qg], v1, o[qg][1], 0, 0, 0);
                o[qg][2] = __builtin_amdgcn_mfma_f32_16x16x32_fp8_fp8(pf[i][qg], v2, o[qg][2], 0, 0, 0);
                o[qg][3] = __builtin_amdgcn_mfma_f32_16x16x32_fp8_fp8(pf[i][qg], v3, o[qg][3], 0, 0, 0);
            }
        }
    };

    int4 kA[4], vA[4], kB[4], vB[4];
    loadPair(kA, kg, 0);
    loadPair(vA, vg, 0);
    #pragma unroll
    for (int mm = 0; mm < 4; ++mm) {     // 8 macro-steps = 16 tiles
        macro(kA, vA, kB, vB, 2 * mm + 1);
        const int nxt = (2 * mm + 2 < 8) ? 2 * mm + 2 : 7;
        macro(kB, vB, kA, vA, nxt);
    }

    // Row denominators: lanes sharing l16 (across quads) hold one row.
    #pragma unroll
    for (int qg = 0; qg < 2; ++qg) {
        l_acc[qg] += __shfl_xor(l_acc[qg], 16);
        l_acc[qg] += __shfl_xor(l_acc[qg], 32);
    }
    if (quad == 0) {
        #pragma unroll
        for (int qg = 0; qg < 2; ++qg)
            C.Lred[qg * 16 + l16][g] = l_acc[qg];
    }

    // Cross-group combine: groups 0-3 write slots, barrier, groups 4-7 add.
    if (g < 4) {
        #pragma unroll
        for (int qg = 0; qg < 2; ++qg)
            #pragma unroll
            for (int nb = 0; nb < 4; ++nb)
                #pragma unroll
                for (int r = 0; r < 4; ++r)
                    C.Ored[qg * 16 + quad * 4 + r][g][nb * 16 + l16] = o[qg][nb][r];
    }
    __syncthreads();
    if (g >= 4) {
        #pragma unroll
        for (int qg = 0; qg < 2; ++qg)
            #pragma unroll
            for (int nb = 0; nb < 4; ++nb)
                #pragma unroll
                for (int r = 0; r < 4; ++r)
                    C.Ored[qg * 16 + quad * 4 + r][g - 4][nb * 16 + l16] += o[qg][nb][r];
    }
    __syncthreads();

    // Epilogue: out = attn@v + q; 3x { x += 2q; sigmoid; clamp }.
    {
        const int row = tid >> 4;
        const int d4  = (tid & 15) * 4;
        float l = 0.0f;
        #pragma unroll
        for (int gg = 0; gg < NG; ++gg) l += C.Lred[row][gg];
        const float rl = 1.0f / l;
        float xs[4] = {0.f, 0.f, 0.f, 0.f};
        #pragma unroll
        for (int s = 0; s < 4; ++s) {
            const float4 t4 = *(const float4*)&C.Ored[row][s][d4];
            xs[0] += t4.x; xs[1] += t4.y; xs[2] += t4.z; xs[3] += t4.w;
        }
        const size_t idx = ((size_t)b * SQd + qbase + row) * DDIM + d4;
        const float4 q4 = *(const float4*)(q + idx);
        const float qs[4] = {q4.x, q4.y, q4.z, q4.w};
        #pragma unroll
        for (int c = 0; c < 4; ++c) {
            float x = xs[c] * rl + qs[c];
            #pragma unroll
            for (int itc = 0; itc < 3; ++itc) {
                x = x + 2.0f * qs[c];
                x = 1.0f / (1.0f + __expf(-x));
                x = fminf(fmaxf(x, 0.0f), 1.0f);
            }
            xs[c] = x;
        }
        const float4 r4 = {xs[0], xs[1], xs[2], xs[3]};
        *(float4*)(out + idx) = r4;
    }
}

extern "C" void kernel_launch(void* const* d_in, const int* in_sizes, int n_in,
                              void* d_out, int out_size, void* d_ws, size_t ws_size,
                              hipStream_t stream) {
    const float* q = (const float*)d_in[0];
    const float* k = (const float*)d_in[1];
    const float* v = (const float*)d_in[2];
    const int* isf = (const int*)d_in[3];
    float* out = (float*)d_out;
    char* ws = (char*)d_ws;   // Kws: 1 MB, Vws: 1 MB (fp8)

    prepack_kernel<<<dim3(4 * NTILES), dim3(256), 0, stream>>>(k, v, ws);

    const int nblocks = 4 * (SQd / BROWS);  // 512 blocks x 512 threads, 2/CU
    fattn_kernel<<<dim3(nblocks), dim3(512), 0, stream>>>(
        q, isf, ws, ws + KWS_BYTES, out);
}